// Round 5
// baseline (200.905 us; speedup 1.0000x reference)
//
#include <hip/hip_runtime.h>

#define HH 128
#define WW 128
#define CIN 256
#define COUT 256
#define KTOT 2304   // 9 * 256, k = kk*256 + ci
#define HW (HH * WW)
#define NIT 36      // 9 taps * 4 channel-chunks of 64

typedef __attribute__((ext_vector_type(8))) short short8;
typedef __attribute__((ext_vector_type(4))) float f32x4;
typedef __attribute__((ext_vector_type(2))) float f32x2;

__device__ __forceinline__ unsigned rne_bf16(float f) {
  unsigned u = __float_as_uint(f);
  return (u + 0x7FFFu + ((u >> 16) & 1u)) >> 16;
}
__device__ __forceinline__ unsigned cvt_pk_bf16(float lo, float hi) {
  unsigned r;
  asm("v_cvt_pk_bf16_f32 %0, %1, %2" : "=v"(r) : "v"(lo), "v"(hi));
  return r;
}
// unpack bf16x2 word -> {lo,hi} as exact f32 pair
__device__ __forceinline__ f32x2 up2(unsigned u) {
  f32x2 r;
  r.x = __uint_as_float(u << 16);
  r.y = __uint_as_float(u & 0xFFFF0000u);
  return r;
}
__device__ __forceinline__ f32x2 pkmul(f32x2 w, f32x2 v) {
  f32x2 d;
  asm("v_pk_mul_f32 %0, %1, %2" : "=v"(d) : "v"(w), "v"(v));
  return d;
}
__device__ __forceinline__ f32x2 pkfma(f32x2 w, f32x2 v, f32x2 c) {
  f32x2 d;
  asm("v_pk_fma_f32 %0, %1, %2, %3" : "=v"(d) : "v"(w), "v"(v), "v"(c));
  return d;
}

// R9 prep (vectorized):
//  blocks [0,2048):    transpose x [N][CIN][H][W] fp32 -> xt [N][H][W][CIN] bf16
//    tile = 64ci x 64w staged in LDS as [w][ci] (pad 68), float4 reads,
//    ds_read_b128 + cvt_pk_bf16 + 16B coalesced stores.
//  blocks [2048,3200): weight [COUT][CIN][3][3] fp32 -> wB MFMA-frag order,
//    2 elems/thread, dword writes.
//    element (co,k): k = it*64 + ksi*32 + l4*8 + e ->
//    wB[(it*32 + (co>>4)*2 + ksi)*512 + (l4*16 + (co&15))*8 + e]
__global__ void prep_inputs(const float* __restrict__ x, const float* __restrict__ wsrc,
                            unsigned short* __restrict__ xt, unsigned short* __restrict__ wB) {
  int b = blockIdx.x;
  __shared__ __align__(16) float tile[64][68];  // [w][ci], 17.4 KB
  int tid = threadIdx.x;
  if (b < 2048) {
    int wg = b & 1, cg = (b >> 1) & 3, nh = b >> 3;
    int n = nh >> 7, h = nh & 127;
    const float* xp = x + (((size_t)n * CIN + cg * 64) * HH + h) * WW + wg * 64;
    // read 64ci x 64w floats as float4; write LDS transposed [w][ci]
#pragma unroll
    for (int r = 0; r < 4; ++r) {
      int e = r * 256 + tid;            // 0..1023
      int ci = e >> 4, w4 = (e & 15) * 4;
      float4 v = *(const float4*)(xp + (size_t)ci * HW + w4);
      tile[w4 + 0][ci] = v.x;
      tile[w4 + 1][ci] = v.y;
      tile[w4 + 2][ci] = v.z;
      tile[w4 + 3][ci] = v.w;
    }
    __syncthreads();
    unsigned short* dst = xt + (((size_t)(n * HH + h) * WW) + wg * 64) * CIN + cg * 64;
#pragma unroll
    for (int r = 0; r < 2; ++r) {
      int e = r * 256 + tid;            // 0..511
      int w = e >> 3, c8 = (e & 7) * 8;
      const float* tp = &tile[w][c8];
      f32x4 lo = *(const f32x4*)tp;
      f32x4 hi = *(const f32x4*)(tp + 4);
      uint4 o;
      o.x = cvt_pk_bf16(lo.x, lo.y);
      o.y = cvt_pk_bf16(lo.z, lo.w);
      o.z = cvt_pk_bf16(hi.x, hi.y);
      o.w = cvt_pk_bf16(hi.z, hi.w);
      *(uint4*)(dst + (size_t)w * CIN + c8) = o;
    }
  } else {
    int o = (b - 2048) * 512 + tid * 2;
    if (o >= COUT * KTOT) return;
    int co = o / KTOT;
    int r = o - co * KTOT;              // even; r == k == kk*256 + ci
    int kk = r >> 8, ci = r & 255;
    int it = r >> 6;
    int rem = r & 63;
    int ksi = rem >> 5;
    int l4 = (rem >> 3) & 3;
    int e = rem & 7;                    // even
    int off = (it * 32 + (co >> 4) * 2 + ksi) * 512 + (l4 * 16 + (co & 15)) * 8 + e;
    float v0 = wsrc[(size_t)(co * CIN + ci) * 9 + kk];
    float v1 = wsrc[(size_t)(co * CIN + ci + 1) * 9 + kk];
    *(unsigned*)(wB + off) = cvt_pk_bf16(v0, v1);
  }
}

// R9 fused: R8 chassis (512x512, 8 waves, 32x64 wave tiles, B-frags from
// global, LDS = A dbuf only, lgkm-only barrier) + bf SOFTWARE-PIPELINED one
// iteration ahead: bf(it+1)[j] loaded right after last MFMA use of bf(it)[j]
// (j-major loop) -> full-iteration latency budget, no vm stall before MFMA.
__global__ __launch_bounds__(512, 4) void fused_deform_gemm(
    const float* __restrict__ obb, const unsigned short* __restrict__ xt,
    const unsigned short* __restrict__ wB, float* __restrict__ out,
    const int* __restrict__ stride_p) {
  int g = blockIdx.x;
  int xcd = g & 7, li = g >> 3;
  int u = xcd * 64 + li;   // 0..511; each XCD gets a contiguous 32-row band
  int mh = u & 1;          // which half of the image row
  int bm = u >> 1;         // row id 0..255
  int n = bm >> 7, h = bm & 127;
  int tid = threadIdx.x;

  // A only: 128B rows, phys byte = row*128 + (colbyte ^ ((row&7)<<4)); dbuf
  __shared__ __align__(16) unsigned short Alds[2][64 * 64];   // 16 KB

  float inv_s = 1.0f / (float)stride_p[0];

  int lane = tid & 63;
  int wv = tid >> 6;          // 0..7
  int wm = (wv & 1) * 32;     // wave pixel base (32px x 64co wave tile)
  int wn = (wv >> 1) * 64;    // wave cout base
  int l15 = lane & 15, l4 = lane >> 4;

  // A-build: 8 lanes per pixel, one 16B (8-channel) chunk per thread.
  int chunk8 = (lane & 7) * 8;
  int p = wv * 8 + (lane >> 3);    // this thread's pixel, 0..63
  int AldsOff = p * 128 + (((lane & 7) * 16) ^ ((p & 7) << 4));

  // per-thread obb params for pixel p
  float cx_, cy_, pa_, pb_, pc_, pd_;
  {
    int w = mh * 64 + p;
    const float* op = obb + ((size_t)n * 5 * HH + h) * WW + w;
    float xc = op[0] * inv_s;
    float yc = op[(size_t)1 * HW] * inv_s;
    float bw = op[(size_t)2 * HW] * inv_s;
    float bh = op[(size_t)3 * HW] * inv_s;
    float th = op[(size_t)4 * HW];
    float sn, cs;
    sincosf(th, &sn, &cs);
    float dw = bw * (1.0f / 3.0f), dh = bh * (1.0f / 3.0f);
    cx_ = xc; cy_ = yc;
    pa_ = dw * cs; pb_ = dh * sn;
    pc_ = dw * sn; pd_ = dh * cs;
  }

  f32x4 acc[2][4] = {};

  // B-frag base: cog = (wv>>1)*4 + j; byte = wB + (it*32 + cog*2 + ksi)*1024 + lane*16
  const char* wBb = (const char*)wB + (wv >> 1) * 8192 + lane * 16;

  // A fragment-read column byte offsets (frag row &7 == l15&7)
  int rdXor = (l15 & 7) << 4;
  int rc0 = (l4 * 16) ^ rdXor;        // ks = 0
  int rc1 = (64 + l4 * 16) ^ rdXor;   // ks = 32

  f32x2 wgt2[4];  // bilinear weights (duplicated pairs)
  int boff[4];    // corner base element offsets
  uint4 pf[4];    // prefetched corner data
  uint4 aw;       // blended A chunk awaiting staging
  short8 bf[8];   // B fragments for CURRENT iter (pipelined one ahead)

  auto prep = [&](int kk) {
    float fky = (float)(kk / 3 - 1);
    float fkx = (float)(kk % 3 - 1);
    float sx = cx_ + fkx * pa_ - fky * pb_;
    float sy = cy_ + fkx * pc_ + fky * pd_;
    float fx = floorf(sx), fy = floorf(sy);
    float lx = sx - fx, ly = sy - fy;
    int x0 = (int)fx, y0 = (int)fy;
    float vy0 = (y0 >= 0 && y0 < HH) ? 1.0f : 0.0f;
    float vy1 = (y0 >= -1 && y0 < HH - 1) ? 1.0f : 0.0f;
    float vx0 = (x0 >= 0 && x0 < WW) ? 1.0f : 0.0f;
    float vx1 = (x0 >= -1 && x0 < WW - 1) ? 1.0f : 0.0f;
    float w00 = (1.0f - ly) * (1.0f - lx) * vy0 * vx0;
    float w01 = (1.0f - ly) * lx * vy0 * vx1;
    float w10 = ly * (1.0f - lx) * vy1 * vx0;
    float w11 = ly * lx * vy1 * vx1;
    wgt2[0] = (f32x2){w00, w00};
    wgt2[1] = (f32x2){w01, w01};
    wgt2[2] = (f32x2){w10, w10};
    wgt2[3] = (f32x2){w11, w11};
    int xc0 = min(max(x0, 0), WW - 1), xc1 = min(max(x0 + 1, 0), WW - 1);
    int yc0 = min(max(y0, 0), HH - 1), yc1 = min(max(y0 + 1, 0), HH - 1);
    int rb0 = (n * HH + yc0) * WW, rb1 = (n * HH + yc1) * WW;
    boff[0] = (rb0 + xc0) * CIN;
    boff[1] = (rb0 + xc1) * CIN;
    boff[2] = (rb1 + xc0) * CIN;
    boff[3] = (rb1 + xc1) * CIN;
  };

  auto issueA = [&](int cc) {
    int co = cc * 64 + chunk8;
#pragma unroll
    for (int c = 0; c < 4; ++c)
      pf[c] = *(const uint4*)(xt + boff[c] + co);
  };

  auto blendW = [&](unsigned a, unsigned b, unsigned c, unsigned d) -> unsigned {
    f32x2 s = pkmul(wgt2[0], up2(a));
    s = pkfma(wgt2[1], up2(b), s);
    s = pkfma(wgt2[2], up2(c), s);
    s = pkfma(wgt2[3], up2(d), s);
    return cvt_pk_bf16(s.x, s.y);
  };

  auto blendA = [&]() {
    uint4 r;
    r.x = blendW(pf[0].x, pf[1].x, pf[2].x, pf[3].x);
    r.y = blendW(pf[0].y, pf[1].y, pf[2].y, pf[3].y);
    r.z = blendW(pf[0].z, pf[1].z, pf[2].z, pf[3].z);
    r.w = blendW(pf[0].w, pf[1].w, pf[2].w, pf[3].w);
    aw = r;
  };

  char* AB = (char*)&Alds[0][0];

  // ---- prologue: stage tile 0; bf(0) in regs; gathers for tile 1 in flight ----
  prep(0);
  issueA(0);
  blendA();
  *(uint4*)(AB + AldsOff) = aw;
#pragma unroll
  for (int j = 0; j < 4; ++j) {
    bf[j * 2 + 0] = *(const short8*)(wBb + j * 2048);
    bf[j * 2 + 1] = *(const short8*)(wBb + j * 2048 + 1024);
  }
  issueA(1);
  asm volatile("s_waitcnt lgkmcnt(0)" ::: "memory");
  __builtin_amdgcn_s_barrier();
  asm volatile("" ::: "memory");

  for (int it = 0; it < NIT; ++it) {
    // ---- blend tile it+1 into nbuf; issue gathers for tile it+2 ----
    if (it + 1 < NIT) {
      blendA();   // consumes pf (oldest vm-ops)
      *(uint4*)(AB + ((it + 1) & 1) * 8192 + AldsOff) = aw;
      int t2 = it + 2;
      if (t2 < NIT) {
        if ((t2 & 3) == 0) prep(t2 >> 2);
        issueA(t2 & 3);   // newest vm-ops: fly through MFMA + barrier
      }
    }

    // ---- MFMA on A[it&1] + bf; j-major, bf(it+1)[j] loaded after last use ----
    char* ABr = AB + (it & 1) * 8192;
    short8 af[2][2];
#pragma unroll
    for (int ksi = 0; ksi < 2; ++ksi) {
      int rc = ksi ? rc1 : rc0;
#pragma unroll
      for (int i = 0; i < 2; ++i)
        af[ksi][i] = *(const short8*)(ABr + (wm + i * 16 + l15) * 128 + rc);
    }
    const char* bpn = wBb + (size_t)((it + 1 < NIT) ? it + 1 : it) * 32768;
    __builtin_amdgcn_s_setprio(1);
#pragma unroll
    for (int j = 0; j < 4; ++j) {
      short8 b0 = bf[j * 2 + 0], b1 = bf[j * 2 + 1];
      acc[0][j] = __builtin_amdgcn_mfma_f32_16x16x32_bf16(af[0][0], b0, acc[0][j], 0, 0, 0);
      acc[1][j] = __builtin_amdgcn_mfma_f32_16x16x32_bf16(af[0][1], b0, acc[1][j], 0, 0, 0);
      acc[0][j] = __builtin_amdgcn_mfma_f32_16x16x32_bf16(af[1][0], b1, acc[0][j], 0, 0, 0);
      acc[1][j] = __builtin_amdgcn_mfma_f32_16x16x32_bf16(af[1][1], b1, acc[1][j], 0, 0, 0);
      // prefetch next iteration's fragments for this j (full-iter latency)
      bf[j * 2 + 0] = *(const short8*)(bpn + j * 2048);
      bf[j * 2 + 1] = *(const short8*)(bpn + j * 2048 + 1024);
    }
    __builtin_amdgcn_s_setprio(0);

    // A-dbuf handoff: LDS ops only -> no vmcnt drain, loads keep flying
    asm volatile("s_waitcnt lgkmcnt(0)" ::: "memory");
    __builtin_amdgcn_s_barrier();
    asm volatile("" ::: "memory");
  }

  // ---- epilogue: out[n][co][h][w], float4 along w ----
  float* outp = out + (size_t)n * COUT * HW + (size_t)h * WW + mh * 64;
#pragma unroll
  for (int i = 0; i < 2; ++i) {
    int w0 = wm + i * 16 + l4 * 4;
#pragma unroll
    for (int j = 0; j < 4; ++j) {
      int co = wn + j * 16 + l15;
      *(f32x4*)(outp + (size_t)co * HW + w0) = acc[i][j];
    }
  }
}

extern "C" void kernel_launch(void* const* d_in, const int* in_sizes, int n_in,
                              void* d_out, int out_size, void* d_ws, size_t ws_size,
                              hipStream_t stream) {
  const float* x = (const float*)d_in[0];
  const float* obb = (const float*)d_in[1];
  const float* wgt = (const float*)d_in[2];
  const int* stridep = (const int*)d_in[3];
  float* out = (float*)d_out;

  unsigned short* xt = (unsigned short*)d_ws;          // 2*128*128*256 bf16 = 16.8 MB
  unsigned short* wB = xt + (size_t)2 * HH * WW * CIN; // 256*2304 bf16 = 1.2 MB

  prep_inputs<<<dim3(2048 + 1152), 256, 0, stream>>>(x, wgt, xt, wB);
  fused_deform_gemm<<<dim3(512), 512, 0, stream>>>(obb, xt, wB, out, stridep);
}

// Round 6
// 162.864 us; speedup vs baseline: 1.2336x; 1.2336x over previous
//
#include <hip/hip_runtime.h>

#define HH 128
#define WW 128
#define CIN 256
#define COUT 256
#define KTOT 2304   // 9 * 256, k = kk*256 + ci
#define HW (HH * WW)
#define NIT 36      // 9 taps * 4 channel-chunks of 64

typedef __attribute__((ext_vector_type(8))) short short8;
typedef __attribute__((ext_vector_type(4))) float f32x4;
typedef __attribute__((ext_vector_type(2))) float f32x2;

__device__ __forceinline__ unsigned rne_bf16(float f) {
  unsigned u = __float_as_uint(f);
  return (u + 0x7FFFu + ((u >> 16) & 1u)) >> 16;
}
__device__ __forceinline__ unsigned cvt_pk_bf16(float lo, float hi) {
  unsigned r;
  asm("v_cvt_pk_bf16_f32 %0, %1, %2" : "=v"(r) : "v"(lo), "v"(hi));
  return r;
}
// unpack bf16x2 word -> {lo,hi} as exact f32 pair
__device__ __forceinline__ f32x2 up2(unsigned u) {
  f32x2 r;
  r.x = __uint_as_float(u << 16);
  r.y = __uint_as_float(u & 0xFFFF0000u);
  return r;
}
__device__ __forceinline__ f32x2 pkmul(f32x2 w, f32x2 v) {
  f32x2 d;
  asm("v_pk_mul_f32 %0, %1, %2" : "=v"(d) : "v"(w), "v"(v));
  return d;
}
__device__ __forceinline__ f32x2 pkfma(f32x2 w, f32x2 v, f32x2 c) {
  f32x2 d;
  asm("v_pk_fma_f32 %0, %1, %2, %3" : "=v"(d) : "v"(w), "v"(v), "v"(c));
  return d;
}

// prep (vectorized, unchanged from R9):
//  blocks [0,2048):    transpose x [N][CIN][H][W] fp32 -> xt [N][H][W][CIN] bf16
//  blocks [2048,3200): weight -> wB MFMA-frag order:
//    element (co,k): k = it*64 + ksi*32 + l4*8 + e ->
//    wB[(it*32 + (co>>4)*2 + ksi)*512 + (l4*16 + (co&15))*8 + e]
__global__ void prep_inputs(const float* __restrict__ x, const float* __restrict__ wsrc,
                            unsigned short* __restrict__ xt, unsigned short* __restrict__ wB) {
  int b = blockIdx.x;
  __shared__ __align__(16) float tile[64][68];  // [w][ci], 17.4 KB
  int tid = threadIdx.x;
  if (b < 2048) {
    int wg = b & 1, cg = (b >> 1) & 3, nh = b >> 3;
    int n = nh >> 7, h = nh & 127;
    const float* xp = x + (((size_t)n * CIN + cg * 64) * HH + h) * WW + wg * 64;
#pragma unroll
    for (int r = 0; r < 4; ++r) {
      int e = r * 256 + tid;            // 0..1023
      int ci = e >> 4, w4 = (e & 15) * 4;
      float4 v = *(const float4*)(xp + (size_t)ci * HW + w4);
      tile[w4 + 0][ci] = v.x;
      tile[w4 + 1][ci] = v.y;
      tile[w4 + 2][ci] = v.z;
      tile[w4 + 3][ci] = v.w;
    }
    __syncthreads();
    unsigned short* dst = xt + (((size_t)(n * HH + h) * WW) + wg * 64) * CIN + cg * 64;
#pragma unroll
    for (int r = 0; r < 2; ++r) {
      int e = r * 256 + tid;            // 0..511
      int w = e >> 3, c8 = (e & 7) * 8;
      const float* tp = &tile[w][c8];
      f32x4 lo = *(const f32x4*)tp;
      f32x4 hi = *(const f32x4*)(tp + 4);
      uint4 o;
      o.x = cvt_pk_bf16(lo.x, lo.y);
      o.y = cvt_pk_bf16(lo.z, lo.w);
      o.z = cvt_pk_bf16(hi.x, hi.y);
      o.w = cvt_pk_bf16(hi.z, hi.w);
      *(uint4*)(dst + (size_t)w * CIN + c8) = o;
    }
  } else {
    int o = (b - 2048) * 512 + tid * 2;
    if (o >= COUT * KTOT) return;
    int co = o / KTOT;
    int r = o - co * KTOT;              // even; r == k == kk*256 + ci
    int kk = r >> 8, ci = r & 255;
    int it = r >> 6;
    int rem = r & 63;
    int ksi = rem >> 5;
    int l4 = (rem >> 3) & 3;
    int e = rem & 7;                    // even
    int off = (it * 32 + (co >> 4) * 2 + ksi) * 512 + (l4 * 16 + (co & 15)) * 8 + e;
    float v0 = wsrc[(size_t)(co * CIN + ci) * 9 + kk];
    float v1 = wsrc[(size_t)(co * CIN + ci + 1) * 9 + kk];
    *(unsigned*)(wB + off) = cvt_pk_bf16(v0, v1);
  }
}

// R10: R9 design with the spill fixed. launch_bounds(512,2) -> VGPR cap >=128
// (R9's (512,4) capped at 64 and spilled the bf pipeline: WRITE 73.8MB).
// Pressure trims: ksi-major MFMA with transient af[2]; bf[2j+ksi] reloaded
// for it+1 immediately after its last use in ksi phase. All global loads
// (gathers, bf) have full-iteration load->use distance; barrier is lgkm-only.
__global__ __launch_bounds__(512, 2) void fused_deform_gemm(
    const float* __restrict__ obb, const unsigned short* __restrict__ xt,
    const unsigned short* __restrict__ wB, float* __restrict__ out,
    const int* __restrict__ stride_p) {
  int g = blockIdx.x;
  int xcd = g & 7, li = g >> 3;
  int u = xcd * 64 + li;   // 0..511; each XCD gets a contiguous 32-row band
  int mh = u & 1;          // which half of the image row
  int bm = u >> 1;         // row id 0..255
  int n = bm >> 7, h = bm & 127;
  int tid = threadIdx.x;

  // A only: 128B rows, phys byte = row*128 + (colbyte ^ ((row&7)<<4)); dbuf
  __shared__ __align__(16) unsigned short Alds[2][64 * 64];   // 16 KB

  float inv_s = 1.0f / (float)stride_p[0];

  int lane = tid & 63;
  int wv = tid >> 6;          // 0..7
  int wm = (wv & 1) * 32;     // wave pixel base (32px x 64co wave tile)
  int wn = (wv >> 1) * 64;    // wave cout base
  int l15 = lane & 15, l4 = lane >> 4;

  // A-build: 8 lanes per pixel, one 16B (8-channel) chunk per thread.
  int chunk8 = (lane & 7) * 8;
  int p = wv * 8 + (lane >> 3);    // this thread's pixel, 0..63
  int AldsOff = p * 128 + (((lane & 7) * 16) ^ ((p & 7) << 4));

  // per-thread obb params for pixel p
  float cx_, cy_, pa_, pb_, pc_, pd_;
  {
    int w = mh * 64 + p;
    const float* op = obb + ((size_t)n * 5 * HH + h) * WW + w;
    float xc = op[0] * inv_s;
    float yc = op[(size_t)1 * HW] * inv_s;
    float bw = op[(size_t)2 * HW] * inv_s;
    float bh = op[(size_t)3 * HW] * inv_s;
    float th = op[(size_t)4 * HW];
    float sn, cs;
    sincosf(th, &sn, &cs);
    float dw = bw * (1.0f / 3.0f), dh = bh * (1.0f / 3.0f);
    cx_ = xc; cy_ = yc;
    pa_ = dw * cs; pb_ = dh * sn;
    pc_ = dw * sn; pd_ = dh * cs;
  }

  f32x4 acc[2][4] = {};

  // B-frag base: cog = (wv>>1)*4 + j; byte = wB + (it*32 + cog*2 + ksi)*1024 + lane*16
  const char* wBb = (const char*)wB + (wv >> 1) * 8192 + lane * 16;

  // A fragment-read column byte offsets (frag row &7 == l15&7)
  int rdXor = (l15 & 7) << 4;
  int rc0 = (l4 * 16) ^ rdXor;        // ks = 0
  int rc1 = (64 + l4 * 16) ^ rdXor;   // ks = 32

  f32x2 wgt2[4];  // bilinear weights (duplicated pairs)
  int boff[4];    // corner base element offsets
  uint4 pf[4];    // prefetched corner data
  uint4 aw;       // blended A chunk awaiting staging
  short8 bf[8];   // B fragments for CURRENT iter (reloaded one-ahead in place)

  auto prep = [&](int kk) {
    float fky = (float)(kk / 3 - 1);
    float fkx = (float)(kk % 3 - 1);
    float sx = cx_ + fkx * pa_ - fky * pb_;
    float sy = cy_ + fkx * pc_ + fky * pd_;
    float fx = floorf(sx), fy = floorf(sy);
    float lx = sx - fx, ly = sy - fy;
    int x0 = (int)fx, y0 = (int)fy;
    float vy0 = (y0 >= 0 && y0 < HH) ? 1.0f : 0.0f;
    float vy1 = (y0 >= -1 && y0 < HH - 1) ? 1.0f : 0.0f;
    float vx0 = (x0 >= 0 && x0 < WW) ? 1.0f : 0.0f;
    float vx1 = (x0 >= -1 && x0 < WW - 1) ? 1.0f : 0.0f;
    float w00 = (1.0f - ly) * (1.0f - lx) * vy0 * vx0;
    float w01 = (1.0f - ly) * lx * vy0 * vx1;
    float w10 = ly * (1.0f - lx) * vy1 * vx0;
    float w11 = ly * lx * vy1 * vx1;
    wgt2[0] = (f32x2){w00, w00};
    wgt2[1] = (f32x2){w01, w01};
    wgt2[2] = (f32x2){w10, w10};
    wgt2[3] = (f32x2){w11, w11};
    int xc0 = min(max(x0, 0), WW - 1), xc1 = min(max(x0 + 1, 0), WW - 1);
    int yc0 = min(max(y0, 0), HH - 1), yc1 = min(max(y0 + 1, 0), HH - 1);
    int rb0 = (n * HH + yc0) * WW, rb1 = (n * HH + yc1) * WW;
    boff[0] = (rb0 + xc0) * CIN;
    boff[1] = (rb0 + xc1) * CIN;
    boff[2] = (rb1 + xc0) * CIN;
    boff[3] = (rb1 + xc1) * CIN;
  };

  auto issueA = [&](int cc) {
    int co = cc * 64 + chunk8;
#pragma unroll
    for (int c = 0; c < 4; ++c)
      pf[c] = *(const uint4*)(xt + boff[c] + co);
  };

  auto blendW = [&](unsigned a, unsigned b, unsigned c, unsigned d) -> unsigned {
    f32x2 s = pkmul(wgt2[0], up2(a));
    s = pkfma(wgt2[1], up2(b), s);
    s = pkfma(wgt2[2], up2(c), s);
    s = pkfma(wgt2[3], up2(d), s);
    return cvt_pk_bf16(s.x, s.y);
  };

  auto blendA = [&]() {
    uint4 r;
    r.x = blendW(pf[0].x, pf[1].x, pf[2].x, pf[3].x);
    r.y = blendW(pf[0].y, pf[1].y, pf[2].y, pf[3].y);
    r.z = blendW(pf[0].z, pf[1].z, pf[2].z, pf[3].z);
    r.w = blendW(pf[0].w, pf[1].w, pf[2].w, pf[3].w);
    aw = r;
  };

  char* AB = (char*)&Alds[0][0];

  // ---- prologue: stage tile 0; bf(0) in regs; gathers for tile 1 in flight ----
  prep(0);
  issueA(0);
  blendA();
  *(uint4*)(AB + AldsOff) = aw;
#pragma unroll
  for (int j = 0; j < 4; ++j) {
    bf[j * 2 + 0] = *(const short8*)(wBb + j * 2048);
    bf[j * 2 + 1] = *(const short8*)(wBb + j * 2048 + 1024);
  }
  issueA(1);
  asm volatile("s_waitcnt lgkmcnt(0)" ::: "memory");
  __builtin_amdgcn_s_barrier();
  asm volatile("" ::: "memory");

  for (int it = 0; it < NIT; ++it) {
    // ---- blend tile it+1 into nbuf; issue gathers for tile it+2 ----
    if (it + 1 < NIT) {
      blendA();   // consumes pf (oldest vm-ops)
      *(uint4*)(AB + ((it + 1) & 1) * 8192 + AldsOff) = aw;
      int t2 = it + 2;
      if (t2 < NIT) {
        if ((t2 & 3) == 0) prep(t2 >> 2);
        issueA(t2 & 3);   // newest vm-ops: fly through MFMA + barrier
      }
    }

    // ---- MFMA on A[it&1] + bf; ksi-major, bf[2j+ksi](it+1) loaded right
    //      after its last use; af transient per ksi ----
    char* ABr = AB + (it & 1) * 8192;
    const char* bpn = wBb + (size_t)((it + 1 < NIT) ? it + 1 : it) * 32768;
    __builtin_amdgcn_s_setprio(1);
    {
      short8 af0 = *(const short8*)(ABr + (wm + l15) * 128 + rc0);
      short8 af1 = *(const short8*)(ABr + (wm + 16 + l15) * 128 + rc0);
#pragma unroll
      for (int j = 0; j < 4; ++j) {
        short8 b0 = bf[j * 2];
        acc[0][j] = __builtin_amdgcn_mfma_f32_16x16x32_bf16(af0, b0, acc[0][j], 0, 0, 0);
        acc[1][j] = __builtin_amdgcn_mfma_f32_16x16x32_bf16(af1, b0, acc[1][j], 0, 0, 0);
        bf[j * 2] = *(const short8*)(bpn + j * 2048);      // next iter, even frag
      }
    }
    {
      short8 af0 = *(const short8*)(ABr + (wm + l15) * 128 + rc1);
      short8 af1 = *(const short8*)(ABr + (wm + 16 + l15) * 128 + rc1);
#pragma unroll
      for (int j = 0; j < 4; ++j) {
        short8 b1 = bf[j * 2 + 1];
        acc[0][j] = __builtin_amdgcn_mfma_f32_16x16x32_bf16(af0, b1, acc[0][j], 0, 0, 0);
        acc[1][j] = __builtin_amdgcn_mfma_f32_16x16x32_bf16(af1, b1, acc[1][j], 0, 0, 0);
        bf[j * 2 + 1] = *(const short8*)(bpn + j * 2048 + 1024);  // next iter, odd frag
      }
    }
    __builtin_amdgcn_s_setprio(0);

    // A-dbuf handoff: LDS ops only -> no vmcnt drain, loads keep flying
    asm volatile("s_waitcnt lgkmcnt(0)" ::: "memory");
    __builtin_amdgcn_s_barrier();
    asm volatile("" ::: "memory");
  }

  // ---- epilogue: out[n][co][h][w], float4 along w ----
  float* outp = out + (size_t)n * COUT * HW + (size_t)h * WW + mh * 64;
#pragma unroll
  for (int i = 0; i < 2; ++i) {
    int w0 = wm + i * 16 + l4 * 4;
#pragma unroll
    for (int j = 0; j < 4; ++j) {
      int co = wn + j * 16 + l15;
      *(f32x4*)(outp + (size_t)co * HW + w0) = acc[i][j];
    }
  }
}

extern "C" void kernel_launch(void* const* d_in, const int* in_sizes, int n_in,
                              void* d_out, int out_size, void* d_ws, size_t ws_size,
                              hipStream_t stream) {
  const float* x = (const float*)d_in[0];
  const float* obb = (const float*)d_in[1];
  const float* wgt = (const float*)d_in[2];
  const int* stridep = (const int*)d_in[3];
  float* out = (float*)d_out;

  unsigned short* xt = (unsigned short*)d_ws;          // 2*128*128*256 bf16 = 16.8 MB
  unsigned short* wB = xt + (size_t)2 * HH * WW * CIN; // 256*2304 bf16 = 1.2 MB

  prep_inputs<<<dim3(2048 + 1152), 256, 0, stream>>>(x, wgt, xt, wB);
  fused_deform_gemm<<<dim3(512), 512, 0, stream>>>(obb, xt, wB, out, stridep);
}

// Round 7
// 153.629 us; speedup vs baseline: 1.3077x; 1.0601x over previous
//
#include <hip/hip_runtime.h>

#define HH 128
#define WW 128
#define CIN 256
#define COUT 256
#define KTOT 2304   // 9 * 256, k = kk*256 + ci
#define HW (HH * WW)
#define NIT 36      // 9 taps * 4 channel-chunks of 64

typedef __attribute__((ext_vector_type(8))) short short8;
typedef __attribute__((ext_vector_type(4))) float f32x4;
typedef __attribute__((ext_vector_type(2))) float f32x2;

__device__ __forceinline__ unsigned rne_bf16(float f) {
  unsigned u = __float_as_uint(f);
  return (u + 0x7FFFu + ((u >> 16) & 1u)) >> 16;
}
__device__ __forceinline__ unsigned cvt_pk_bf16(float lo, float hi) {
  unsigned r;
  asm("v_cvt_pk_bf16_f32 %0, %1, %2" : "=v"(r) : "v"(lo), "v"(hi));
  return r;
}
// unpack bf16x2 word -> {lo,hi} as exact f32 pair
__device__ __forceinline__ f32x2 up2(unsigned u) {
  f32x2 r;
  r.x = __uint_as_float(u << 16);
  r.y = __uint_as_float(u & 0xFFFF0000u);
  return r;
}
__device__ __forceinline__ f32x2 pkmul(f32x2 w, f32x2 v) {
  f32x2 d;
  asm("v_pk_mul_f32 %0, %1, %2" : "=v"(d) : "v"(w), "v"(v));
  return d;
}
__device__ __forceinline__ f32x2 pkfma(f32x2 w, f32x2 v, f32x2 c) {
  f32x2 d;
  asm("v_pk_fma_f32 %0, %1, %2, %3" : "=v"(d) : "v"(w), "v"(v), "v"(c));
  return d;
}

__device__ __forceinline__ void glds16(const void* g, void* l) {
  __builtin_amdgcn_global_load_lds(
      (const __attribute__((address_space(1))) void*)g,
      (__attribute__((address_space(3))) void*)l, 16, 0, 0);
}

// prep (vectorized):
//  blocks [0,2048):    transpose x [N][CIN][H][W] fp32 -> xt [N][H][W][CIN] bf16
//  blocks [2048,3200): weight [COUT][CIN][3][3] fp32 -> wT [COUT][kk*256+ci] bf16
__global__ void prep_inputs(const float* __restrict__ x, const float* __restrict__ wsrc,
                            unsigned short* __restrict__ xt, unsigned short* __restrict__ wT) {
  int b = blockIdx.x;
  __shared__ __align__(16) float tile[64][68];  // [w][ci], 17.4 KB
  int tid = threadIdx.x;
  if (b < 2048) {
    int wg = b & 1, cg = (b >> 1) & 3, nh = b >> 3;
    int n = nh >> 7, h = nh & 127;
    const float* xp = x + (((size_t)n * CIN + cg * 64) * HH + h) * WW + wg * 64;
#pragma unroll
    for (int r = 0; r < 4; ++r) {
      int e = r * 256 + tid;            // 0..1023
      int ci = e >> 4, w4 = (e & 15) * 4;
      float4 v = *(const float4*)(xp + (size_t)ci * HW + w4);
      tile[w4 + 0][ci] = v.x;
      tile[w4 + 1][ci] = v.y;
      tile[w4 + 2][ci] = v.z;
      tile[w4 + 3][ci] = v.w;
    }
    __syncthreads();
    unsigned short* dst = xt + (((size_t)(n * HH + h) * WW) + wg * 64) * CIN + cg * 64;
#pragma unroll
    for (int r = 0; r < 2; ++r) {
      int e = r * 256 + tid;            // 0..511
      int w = e >> 3, c8 = (e & 7) * 8;
      const float* tp = &tile[w][c8];
      f32x4 lo = *(const f32x4*)tp;
      f32x4 hi = *(const f32x4*)(tp + 4);
      uint4 o;
      o.x = cvt_pk_bf16(lo.x, lo.y);
      o.y = cvt_pk_bf16(lo.z, lo.w);
      o.z = cvt_pk_bf16(hi.x, hi.y);
      o.w = cvt_pk_bf16(hi.z, hi.w);
      *(uint4*)(dst + (size_t)w * CIN + c8) = o;
    }
  } else {
    int o = (b - 2048) * 512 + tid * 2;
    if (o >= COUT * KTOT) return;
    int co = o / KTOT;
    int r = o - co * KTOT;              // even; r == k == kk*256 + ci
    int kk = r >> 8, ci = r & 255;
    float v0 = wsrc[(size_t)(co * CIN + ci) * 9 + kk];
    float v1 = wsrc[(size_t)(co * CIN + ci + 1) * 9 + kk];
    *(unsigned*)(wT + o) = cvt_pk_bf16(v0, v1);
  }
}

// R11: R6's shared-B-via-glds (kills R10's 16x-redundant per-wave global B
// traffic: TA ops 192->128/CU/iter) + R10's full-dbuf single-barrier with
// counted vmcnt(4) (kills R6's vmcnt(0) drain + second barrier).
// LDS 80KB/block (A dbuf 16K + B dbuf 64K) = exactly 2 blocks/CU (160KB).
// Queue order per iter: [glds-B(4)] then [gathers(4), newest] -> vmcnt(4)
// at the barrier drains glds, leaves gathers flying.
__global__ __launch_bounds__(512, 2) void fused_deform_gemm(
    const float* __restrict__ obb, const unsigned short* __restrict__ xt,
    const unsigned short* __restrict__ wT, float* __restrict__ out,
    const int* __restrict__ stride_p) {
  int g = blockIdx.x;
  int xcd = g & 7, li = g >> 3;
  int u = xcd * 64 + li;   // 0..511; each XCD gets a contiguous 32-row band
  int mh = u & 1;          // which half of the image row
  int bm = u >> 1;         // row id 0..255
  int n = bm >> 7, h = bm & 127;
  int tid = threadIdx.x;

  // 128B rows, phys byte = row*128 + (colbyte ^ ((row&7)<<4)); both dbuf
  __shared__ __align__(16) unsigned short Alds[2][64 * 64];    // 16 KB
  __shared__ __align__(16) unsigned short Blds[2][256 * 64];   // 64 KB

  float inv_s = 1.0f / (float)stride_p[0];

  int lane = tid & 63;
  int wv = tid >> 6;          // 0..7
  int wm = (wv & 1) * 32;     // wave pixel base (32px x 64co wave tile)
  int wn = (wv >> 1) * 64;    // wave cout base
  int l15 = lane & 15, l4 = lane >> 4;

  // A-build: 8 lanes per pixel, one 16B (8-channel) chunk per thread.
  int chunk8 = (lane & 7) * 8;
  int p = wv * 8 + (lane >> 3);    // this thread's pixel, 0..63
  int AldsOff = p * 128 + (((lane & 7) * 16) ^ ((p & 7) << 4));

  // B staging via glds: 4 wave-ops/iter; lane -> row t*64 + wv*8 + (lane>>3),
  // phys col (lane&7)*16; source pre-swizzled (involution == read XOR).
  int cbl = ((lane & 7) * 16) ^ (((lane >> 3) & 7) << 4);
  const char* wTb = (const char*)wT + (wv * 8 + (lane >> 3)) * (KTOT * 2) + cbl;
  int BldsC[4];   // wave-uniform LDS byte offsets
#pragma unroll
  for (int t = 0; t < 4; ++t) BldsC[t] = (t * 64 + wv * 8) * 128;

  // per-thread obb params for pixel p
  float cx_, cy_, pa_, pb_, pc_, pd_;
  {
    int w = mh * 64 + p;
    const float* op = obb + ((size_t)n * 5 * HH + h) * WW + w;
    float xc = op[0] * inv_s;
    float yc = op[(size_t)1 * HW] * inv_s;
    float bw = op[(size_t)2 * HW] * inv_s;
    float bh = op[(size_t)3 * HW] * inv_s;
    float th = op[(size_t)4 * HW];
    float sn, cs;
    sincosf(th, &sn, &cs);
    float dw = bw * (1.0f / 3.0f), dh = bh * (1.0f / 3.0f);
    cx_ = xc; cy_ = yc;
    pa_ = dw * cs; pb_ = dh * sn;
    pc_ = dw * sn; pd_ = dh * cs;
  }

  f32x4 acc[2][4] = {};

  // fragment-read column byte offsets (frag row &7 == l15&7)
  int rdXor = (l15 & 7) << 4;
  int rc0 = (l4 * 16) ^ rdXor;        // ks = 0
  int rc1 = (64 + l4 * 16) ^ rdXor;   // ks = 32

  f32x2 wgt2[4];  // bilinear weights (duplicated pairs)
  int boff[4];    // corner base element offsets
  uint4 pf[4];    // prefetched corner data
  uint4 aw;       // blended A chunk awaiting staging

  auto prep = [&](int kk) {
    float fky = (float)(kk / 3 - 1);
    float fkx = (float)(kk % 3 - 1);
    float sx = cx_ + fkx * pa_ - fky * pb_;
    float sy = cy_ + fkx * pc_ + fky * pd_;
    float fx = floorf(sx), fy = floorf(sy);
    float lx = sx - fx, ly = sy - fy;
    int x0 = (int)fx, y0 = (int)fy;
    float vy0 = (y0 >= 0 && y0 < HH) ? 1.0f : 0.0f;
    float vy1 = (y0 >= -1 && y0 < HH - 1) ? 1.0f : 0.0f;
    float vx0 = (x0 >= 0 && x0 < WW) ? 1.0f : 0.0f;
    float vx1 = (x0 >= -1 && x0 < WW - 1) ? 1.0f : 0.0f;
    float w00 = (1.0f - ly) * (1.0f - lx) * vy0 * vx0;
    float w01 = (1.0f - ly) * lx * vy0 * vx1;
    float w10 = ly * (1.0f - lx) * vy1 * vx0;
    float w11 = ly * lx * vy1 * vx1;
    wgt2[0] = (f32x2){w00, w00};
    wgt2[1] = (f32x2){w01, w01};
    wgt2[2] = (f32x2){w10, w10};
    wgt2[3] = (f32x2){w11, w11};
    int xc0 = min(max(x0, 0), WW - 1), xc1 = min(max(x0 + 1, 0), WW - 1);
    int yc0 = min(max(y0, 0), HH - 1), yc1 = min(max(y0 + 1, 0), HH - 1);
    int rb0 = (n * HH + yc0) * WW, rb1 = (n * HH + yc1) * WW;
    boff[0] = (rb0 + xc0) * CIN;
    boff[1] = (rb0 + xc1) * CIN;
    boff[2] = (rb1 + xc0) * CIN;
    boff[3] = (rb1 + xc1) * CIN;
  };

  auto issueA = [&](int cc) {
    int co = cc * 64 + chunk8;
#pragma unroll
    for (int c = 0; c < 4; ++c)
      pf[c] = *(const uint4*)(xt + boff[c] + co);
  };

  auto blendW = [&](unsigned a, unsigned b, unsigned c, unsigned d) -> unsigned {
    f32x2 s = pkmul(wgt2[0], up2(a));
    s = pkfma(wgt2[1], up2(b), s);
    s = pkfma(wgt2[2], up2(c), s);
    s = pkfma(wgt2[3], up2(d), s);
    return cvt_pk_bf16(s.x, s.y);
  };

  auto blendA = [&]() {
    uint4 r;
    r.x = blendW(pf[0].x, pf[1].x, pf[2].x, pf[3].x);
    r.y = blendW(pf[0].y, pf[1].y, pf[2].y, pf[3].y);
    r.z = blendW(pf[0].z, pf[1].z, pf[2].z, pf[3].z);
    r.w = blendW(pf[0].w, pf[1].w, pf[2].w, pf[3].w);
    aw = r;
  };

  char* AB = (char*)&Alds[0][0];
  char* BB = (char*)&Blds[0][0];

  auto stageB = [&](int itn, int nbuf) {
    const char* src = wTb + itn * 128;
    char* Bd = BB + nbuf * 32768;
#pragma unroll
    for (int t = 0; t < 4; ++t)
      glds16(src + t * (64 * KTOT * 2), Bd + BldsC[t]);
  };

  // ---- prologue: stage tile 0 into buf0; gathers(1) in flight ----
  prep(0);
  issueA(0);
  blendA();
  *(uint4*)(AB + AldsOff) = aw;
  stageB(0, 0);
  issueA(1);   // newest 4 vm-ops
  asm volatile("s_waitcnt vmcnt(4) lgkmcnt(0)" ::: "memory");
  __builtin_amdgcn_s_barrier();
  asm volatile("" ::: "memory");

  for (int it = 0; it < NIT; ++it) {
    int buf = it & 1, nbuf = buf ^ 1;

    // ---- staging for it+1; gathers for it+2 issued LAST (stay in flight) ----
    if (it + 1 < NIT) {
      blendA();   // consumes pf (tile it+1 data; only outstanding vm-ops)
      *(uint4*)(AB + nbuf * 8192 + AldsOff) = aw;
      stageB(it + 1, nbuf);
      int t2 = it + 2;
      if (t2 < NIT) {
        if ((t2 & 3) == 0) prep(t2 >> 2);
        issueA(t2 & 3);
      }
    }

    // ---- MFMA on buf (A and B from LDS, swizzled conflict-free) ----
    char* ABr = AB + buf * 8192;
    char* BBr = BB + buf * 32768;
    __builtin_amdgcn_s_setprio(1);
#pragma unroll
    for (int ksi = 0; ksi < 2; ++ksi) {
      int rc = ksi ? rc1 : rc0;
      short8 af0 = *(const short8*)(ABr + (wm + l15) * 128 + rc);
      short8 af1 = *(const short8*)(ABr + (wm + 16 + l15) * 128 + rc);
#pragma unroll
      for (int j = 0; j < 4; ++j) {
        short8 bf = *(const short8*)(BBr + (wn + j * 16 + l15) * 128 + rc);
        acc[0][j] = __builtin_amdgcn_mfma_f32_16x16x32_bf16(af0, bf, acc[0][j], 0, 0, 0);
        acc[1][j] = __builtin_amdgcn_mfma_f32_16x16x32_bf16(af1, bf, acc[1][j], 0, 0, 0);
      }
    }
    __builtin_amdgcn_s_setprio(0);

    // ---- barrier: drain glds + LDS ops; keep gathers flying ----
    if (it + 1 < NIT) {
      if (it + 2 < NIT) {
        asm volatile("s_waitcnt vmcnt(4) lgkmcnt(0)" ::: "memory");
      } else {
        asm volatile("s_waitcnt vmcnt(0) lgkmcnt(0)" ::: "memory");
      }
      __builtin_amdgcn_s_barrier();
      asm volatile("" ::: "memory");
    }
  }

  // ---- epilogue: out[n][co][h][w], float4 along w ----
  float* outp = out + (size_t)n * COUT * HW + (size_t)h * WW + mh * 64;
#pragma unroll
  for (int i = 0; i < 2; ++i) {
    int w0 = wm + i * 16 + l4 * 4;
#pragma unroll
    for (int j = 0; j < 4; ++j) {
      int co = wn + j * 16 + l15;
      *(f32x4*)(outp + (size_t)co * HW + w0) = acc[i][j];
    }
  }
}

extern "C" void kernel_launch(void* const* d_in, const int* in_sizes, int n_in,
                              void* d_out, int out_size, void* d_ws, size_t ws_size,
                              hipStream_t stream) {
  const float* x = (const float*)d_in[0];
  const float* obb = (const float*)d_in[1];
  const float* wgt = (const float*)d_in[2];
  const int* stridep = (const int*)d_in[3];
  float* out = (float*)d_out;

  unsigned short* xt = (unsigned short*)d_ws;          // 2*128*128*256 bf16 = 16.8 MB
  unsigned short* wT = xt + (size_t)2 * HH * WW * CIN; // 256*2304 bf16 = 1.2 MB

  prep_inputs<<<dim3(2048 + 1152), 256, 0, stream>>>(x, wgt, xt, wT);
  fused_deform_gemm<<<dim3(512), 512, 0, stream>>>(obb, xt, wT, out, stridep);
}